// Round 6
// baseline (199.097 us; speedup 1.0000x reference)
//
#include <hip/hip_runtime.h>
#include <stdint.h>

// graphConv: out[b] = (sum_k W_k S^k) @ X_b ; B=128, N=1024, D=64, K=8
//
// All-fp16 tree (fp32 MFMA accumulate), 5 launches:
//   prep: cvt S (rm+cm), W1,W3,W5,W7 (rm) -> fp16 + transpose X -> XT
//   L1: S2 = S*S (rm+cm) ; U_j = W_{2j}(fp32 acc-preload) + W_{2j+1}*S
//   L2: S4 = S2*S2 (cm) ; V0 = U0 + U1*S2 ; V1 = U2 + U3*S2
//   L3: A = V0(fp16 acc-preload) + V1*S4
//   apply: out = A @ X as ONE 1024 x 8192 x 1024 GEMM
//
// R6 change: tree GEMMs are SINGLE-WAVE 64x64 blocks, BARRIER-FREE.
// One wave owns the whole tile -> no inter-wave rendezvous: zero
// s_barrier in the K-loop. Pipeline discipline is the wave's own
// counted waitcnts: prologue stages tiles 0,1 (32 loads); each step
// waits vmcnt(16) (tile k landed, k+1 in flight = prefetch distance 2,
// ~700 cyc of compute cover), reads 16 ds_read_b128 frags, lgkmcnt(0),
// re-stages the consumed buffer with tile k+2, then 32 MFMAs.
// Ratio 0.5 ds_read/MFMA at only 32 KB LDS (5 blocks/CU for L1).
// Apply keeps R5's 128^2 4-wave counted-vmcnt structure (unchanged).
// XOR-swizzled 128B LDS rows (conflict-free), global_load_lds w=16.

#define NN 1024
#define NBATCH 128
#define DDIM 64

typedef float floatx4 __attribute__((ext_vector_type(4)));
typedef _Float16 f16x8 __attribute__((ext_vector_type(8)));
typedef unsigned short u16;

__device__ __forceinline__ u16 f2h(float f) {
  union { _Float16 h; u16 u; } v; v.h = (_Float16)f; return v.u;
}
__device__ __forceinline__ float h2f(u16 u) {
  union { _Float16 h; u16 u; } v; v.u = u; return (float)v.h;
}

__device__ __forceinline__ void gll16(const void* g, void* l) {
  __builtin_amdgcn_global_load_lds(
      (const __attribute__((address_space(1))) void*)g,
      (__attribute__((address_space(3))) void*)l, 16, 0, 0);
}

// Wait until at most N VMEM ops outstanding, then barrier (multi-wave
// kernels). Counted N>0 keeps the just-issued prefetch in flight (T4).
template <int N>
__device__ __forceinline__ void wait_vm_barrier() {
  static_assert(N == 0 || N == 8, "literal table");
  if constexpr (N == 0) asm volatile("s_waitcnt vmcnt(0)" ::: "memory");
  else if constexpr (N == 8) asm volatile("s_waitcnt vmcnt(8)" ::: "memory");
  asm volatile("s_barrier" ::: "memory");
}

__device__ __forceinline__ void wait_lgkm_barrier() {
  asm volatile("s_waitcnt lgkmcnt(0)" ::: "memory");
  asm volatile("s_barrier" ::: "memory");
}

// Stage ROWS x 64 u16 tile (row stride NN) into linear LDS, 16B chunks
// XOR-swizzled by row&7 (4-wave version, for apply_gemm).
template <int ROWS>
__device__ __forceinline__ void stage64(const u16* __restrict__ g, u16* lds,
                                        int wave, int lane) {
  const int r = lane >> 3, c = lane & 7;
  const int sw = (c ^ r) * 8;
#pragma unroll
  for (int i = 0; i < ROWS / 32; ++i) {
    const int rb = wave * (ROWS / 4) + i * 8;
    gll16(g + (size_t)(rb + r) * NN + sw, lds + rb * 64);
  }
}

// ---------------- prep: cvt fp32->fp16 (5 jobs) + transpose X --------------
struct CvtJob { const float* src; u16* rm; u16* cm; };
struct CvtJobs { CvtJob j[5]; };

// blocks [0,5120): cvt (job = bid>>10); blocks [5120,7168): transpose X.
__global__ __launch_bounds__(256) void prep_kernel(CvtJobs jobs,
                                                   const float* __restrict__ X,
                                                   u16* __restrict__ XT) {
  __shared__ u16 T[64][72];
  const int bid = blockIdx.x;
  const int t = threadIdx.x;
  if (bid < 5120) {
    CvtJob jb = jobs.j[bid >> 10];
    int idx4 = (bid & 1023) * 256 + t;
    int e = idx4 * 4;
    int row = e >> 10, col = e & (NN - 1);
    float4 f = ((const float4*)jb.src)[idx4];
    u16 h[4] = { f2h(f.x), f2h(f.y), f2h(f.z), f2h(f.w) };
    uint2 p;
    p.x = (uint32_t)h[0] | ((uint32_t)h[1] << 16);
    p.y = (uint32_t)h[2] | ((uint32_t)h[3] << 16);
    *(uint2*)&jb.rm[e] = p;
    if (jb.cm) {
#pragma unroll
      for (int i = 0; i < 4; ++i) jb.cm[(size_t)(col + i) * NN + row] = h[i];
    }
  } else {
    const int tb = bid - 5120;
    const int k0 = (tb & 15) * 64;
    const int b = tb >> 4;
#pragma unroll
    for (int it = 0; it < 4; ++it) {
      int kr = (t >> 4) + it * 16;
      int d4 = (t & 15) * 4;
      float4 f = *(const float4*)&X[((size_t)b * NN + k0 + kr) * DDIM + d4];
      T[d4 + 0][kr] = f2h(f.x);
      T[d4 + 1][kr] = f2h(f.y);
      T[d4 + 2][kr] = f2h(f.z);
      T[d4 + 3][kr] = f2h(f.w);
    }
    __syncthreads();
#pragma unroll
    for (int it = 0; it < 2; ++it) {
      int d = (t >> 3) + it * 32;
      int kc = (t & 7) * 8;
      *(uint4*)&XT[((size_t)b * DDIM + d) * NN + k0 + kc] = *(uint4*)&T[d][kc];
    }
  }
}

// ---------------- tree GEMM: single-wave 64x64, barrier-free ---------------
struct GemmJob {
  const u16* A;        // fp16 row-major MxK
  const u16* B;        // fp16 col-major: (k,n) at [n*NN+k]
  const float* addF;   // optional fp32 additive (row-major, acc-preloaded)
  const u16* addH;     // optional fp16 additive (row-major, acc-preloaded)
  u16* outRm;          // optional fp16 row-major out
  u16* outCm;          // optional fp16 col-major out
};
struct GemmJobs { GemmJob j[5]; };

__global__ __launch_bounds__(64) void gemm_sw(GemmJobs jobs) {
  const GemmJob jb = jobs.j[blockIdx.z];
  __shared__ u16 As[2][64 * 64], Bs[2][64 * 64];  // 32 KB
  const int lane = threadIdx.x;
  const int lm = lane & 15, q = lane >> 4;
  const int r8 = lane >> 3, c8 = lane & 7;
  const int sw = (c8 ^ r8) * 8;
  const int bm = blockIdx.x * 64, bn = blockIdx.y * 64;
  floatx4 acc[4][4] = {};

  const u16* Ag = jb.A + (size_t)bm * NN;
  const u16* Bg = jb.B + (size_t)bn * NN;

  // Preload additive operand into acc fragments (latency hides under K-loop)
  if (jb.addF) {
#pragma unroll
    for (int mi = 0; mi < 4; ++mi)
#pragma unroll
      for (int ni = 0; ni < 4; ++ni)
#pragma unroll
        for (int rr = 0; rr < 4; ++rr) {
          int row = bm + mi * 16 + q * 4 + rr;
          int col = bn + ni * 16 + lm;
          acc[mi][ni][rr] = jb.addF[(size_t)row * NN + col];
        }
  } else if (jb.addH) {
#pragma unroll
    for (int mi = 0; mi < 4; ++mi)
#pragma unroll
      for (int ni = 0; ni < 4; ++ni)
#pragma unroll
        for (int rr = 0; rr < 4; ++rr) {
          int row = bm + mi * 16 + q * 4 + rr;
          int col = bn + ni * 16 + lm;
          acc[mi][ni][rr] = h2f(jb.addH[(size_t)row * NN + col]);
        }
  }

  // stage one 64x64 u16 slab (8 gll16, 8 rows each)
  auto stage = [&](const u16* __restrict__ g, u16* lds) {
#pragma unroll
    for (int i = 0; i < 8; ++i)
      gll16(g + (size_t)(i * 8 + r8) * NN + sw, lds + i * 8 * 64);
  };

  stage(Ag, As[0]);       // tile 0: 16 loads
  stage(Bg, Bs[0]);
  stage(Ag + 64, As[1]);  // tile 1: 16 loads
  stage(Bg + 64, Bs[1]);

  for (int kk = 0; kk < 16; ++kk) {
    const int cur = kk & 1;
    // tile kk's 16 loads landed; tile kk+1's 16 stay in flight
    if (kk < 15)
      asm volatile("s_waitcnt vmcnt(16)" ::: "memory");
    else
      asm volatile("s_waitcnt vmcnt(0)" ::: "memory");
    f16x8 af[2][4], bf[2][4];
#pragma unroll
    for (int ks = 0; ks < 2; ++ks) {
      const int st = ((ks * 4 + q) ^ (lm & 7)) * 8;
#pragma unroll
      for (int i = 0; i < 4; ++i) {
        af[ks][i] = *(const f16x8*)&As[cur][(i * 16 + lm) * 64 + st];
        bf[ks][i] = *(const f16x8*)&Bs[cur][(i * 16 + lm) * 64 + st];
      }
    }
    // frags in regs -> safe to overwrite buf[cur] with tile kk+2
    asm volatile("s_waitcnt lgkmcnt(0)" ::: "memory");
    if (kk + 2 < 16) {
      stage(Ag + (kk + 2) * 64, As[cur]);
      stage(Bg + (kk + 2) * 64, Bs[cur]);
    }
#pragma unroll
    for (int ks = 0; ks < 2; ++ks)
#pragma unroll
      for (int mi = 0; mi < 4; ++mi)
#pragma unroll
        for (int ni = 0; ni < 4; ++ni)
          acc[mi][ni] = __builtin_amdgcn_mfma_f32_16x16x32_f16(
              af[ks][mi], bf[ks][ni], acc[mi][ni], 0, 0, 0);
  }

#pragma unroll
  for (int mi = 0; mi < 4; ++mi)
#pragma unroll
    for (int ni = 0; ni < 4; ++ni)
#pragma unroll
      for (int rr = 0; rr < 4; ++rr) {
        int row = bm + mi * 16 + q * 4 + rr;
        int col = bn + ni * 16 + lm;
        size_t rm = (size_t)row * NN + col;
        u16 h = f2h(acc[mi][ni][rr]);
        if (jb.outRm) jb.outRm[rm] = h;
        if (jb.outCm) jb.outCm[(size_t)col * NN + row] = h;
      }
}

// ---------------- apply: one 1024 x 8192 x 1024 GEMM -----------------------
// cols c = b*64 + d ; XT[c][k] is exactly the col-major B operand.
// 128x128 tiles, 4 waves of 64x64 (MI=NI=4), counted-vmcnt dbuf.
// grid(x=coltile 64, y=rowtile 8): XCD = x%8 -> per XCD: 8 XT coltiles
// (2 MB) + full A (2 MB) L2-resident; 512 blocks = exactly 2/CU.
__global__ __launch_bounds__(256) void apply_gemm(const u16* __restrict__ A,
                                                  const u16* __restrict__ XT,
                                                  float* __restrict__ out) {
  __shared__ u16 As[2][128 * 64], Xs[2][128 * 64];  // 64 KB
  const int t = threadIdx.x, wave = t >> 6, lane = t & 63;
  const int wm = wave >> 1, wn = wave & 1;
  const int lm = lane & 15, q = lane >> 4;
  const int bn = blockIdx.x * 128;  // column tile (b*64+d)
  const int bm = blockIdx.y * 128;  // A row tile
  floatx4 acc[4][4] = {};
  const u16* Ag = A + (size_t)bm * NN;
  const u16* Xg = XT + (size_t)bn * NN;

  stage64<128>(Ag, As[0], wave, lane);
  stage64<128>(Xg, Xs[0], wave, lane);

  for (int kt = 0; kt < 16; ++kt) {
    const int cur = kt & 1;
    if (kt + 1 < 16) {
      stage64<128>(Ag + (kt + 1) * 64, As[cur ^ 1], wave, lane);
      stage64<128>(Xg + (kt + 1) * 64, Xs[cur ^ 1], wave, lane);
      wait_vm_barrier<8>();  // tile kt landed; kt+1's 8 loads in flight
    } else {
      wait_vm_barrier<0>();
    }
#pragma unroll
    for (int ks = 0; ks < 2; ++ks) {
      const int st = ((ks * 4 + q) ^ (lm & 7)) * 8;
      f16x8 xf[4];
#pragma unroll
      for (int ni = 0; ni < 4; ++ni)
        xf[ni] = *(const f16x8*)&Xs[cur][(wn * 64 + ni * 16 + lm) * 64 + st];
#pragma unroll
      for (int mi = 0; mi < 4; ++mi) {
        f16x8 a = *(const f16x8*)&As[cur][(wm * 64 + mi * 16 + lm) * 64 + st];
#pragma unroll
        for (int ni = 0; ni < 4; ++ni)
          acc[mi][ni] = __builtin_amdgcn_mfma_f32_16x16x32_f16(a, xf[ni], acc[mi][ni], 0, 0, 0);
      }
    }
    wait_lgkm_barrier();
  }

#pragma unroll
  for (int mi = 0; mi < 4; ++mi)
#pragma unroll
    for (int ni = 0; ni < 4; ++ni)
#pragma unroll
      for (int r = 0; r < 4; ++r) {
        int row = bm + wm * 64 + mi * 16 + q * 4 + r;
        int col = bn + wn * 64 + ni * 16 + lm;  // = b*64 + d
        out[((size_t)(col >> 6) * NN + row) * DDIM + (col & 63)] =
            acc[mi][ni][r];
      }
}

extern "C" void kernel_launch(void* const* d_in, const int* in_sizes, int n_in,
                              void* d_out, int out_size, void* d_ws, size_t ws_size,
                              hipStream_t stream) {
  const float* nodes  = (const float*)d_in[0];  // [128,1024,64]
  const float* weight = (const float*)d_in[1];  // [8,1024,1024]
  const float* gs     = (const float*)d_in[2];  // [1024,1024]
  float* out = (float*)d_out;
  u16* ws = (u16*)d_ws;
  const size_t MB = (size_t)NN * NN;
  auto buf = [&](int i) -> u16* { return ws + (size_t)i * MB; };
  // 2MB fp16 slots: 0 S rm | 1 S cm | 2..5 W1,3,5,7 rm | 6 S2 rm | 7 S2 cm
  // 8..11 U0..U3 | 12 S4 cm | 13 V0 | 14 V1 | 15 A | 16..23 XT (16 MB)

  u16* XT = buf(16);
  CvtJobs cv{};
  cv.j[0] = { gs,              buf(0), buf(1) };
  cv.j[1] = { weight + 1 * MB, buf(2), nullptr };
  cv.j[2] = { weight + 3 * MB, buf(3), nullptr };
  cv.j[3] = { weight + 5 * MB, buf(4), nullptr };
  cv.j[4] = { weight + 7 * MB, buf(5), nullptr };
  prep_kernel<<<dim3(5120 + 2048), 256, 0, stream>>>(cv, nodes, XT);

  // L1: S2 = S*S ; U_j = W_{2j}(acc-preload) + W_{2j+1}*S
  // 1280 single-wave blocks = 5 blocks/CU (32 KB LDS each)
  GemmJobs g1{};
  g1.j[0] = { buf(0), buf(1), nullptr,         nullptr, buf(6),  buf(7)  };
  g1.j[1] = { buf(2), buf(1), weight + 0 * MB, nullptr, buf(8),  nullptr };
  g1.j[2] = { buf(3), buf(1), weight + 2 * MB, nullptr, buf(9),  nullptr };
  g1.j[3] = { buf(4), buf(1), weight + 4 * MB, nullptr, buf(10), nullptr };
  g1.j[4] = { buf(5), buf(1), weight + 6 * MB, nullptr, buf(11), nullptr };
  gemm_sw<<<dim3(16, 16, 5), 64, 0, stream>>>(g1);

  // L2: S4 = S2*S2 (cm) ; V0 = U0 + U1*S2 ; V1 = U2 + U3*S2  (768 blocks)
  GemmJobs g2{};
  g2.j[0] = { buf(6),  buf(7), nullptr, nullptr, nullptr, buf(12) };
  g2.j[1] = { buf(9),  buf(7), nullptr, buf(8),  buf(13), nullptr };
  g2.j[2] = { buf(11), buf(7), nullptr, buf(10), buf(14), nullptr };
  gemm_sw<<<dim3(16, 16, 3), 64, 0, stream>>>(g2);

  // L3: A = V0(fp16 acc-preload) + V1*S4 -- direct write (256 blocks)
  GemmJobs g3{};
  g3.j[0] = { buf(14), buf(12), nullptr, buf(13), buf(15), nullptr };
  gemm_sw<<<dim3(16, 16, 1), 64, 0, stream>>>(g3);

  apply_gemm<<<dim3(64, 8), 256, 0, stream>>>(buf(15), XT, out);
}

// Round 7
// 173.225 us; speedup vs baseline: 1.1494x; 1.1494x over previous
//
#include <hip/hip_runtime.h>
#include <stdint.h>

// graphConv: out[b] = (sum_k W_k S^k) @ X_b ; B=128, N=1024, D=64, K=8
//
// All-fp16 tree (fp32 MFMA accumulate), 5 launches:
//   prep: S cvt+transpose (rm+cm, coalesced via LDS), W1,3,5,7 cvt (rm),
//         X transpose -> XT [B*D,K] fp16 -- one fused launch, 6400 blocks
//   L1: S2 = S*S (rm+cm) ; U_j = W_{2j}(fp32 acc-preload) + W_{2j+1}*S
//   L2: S4 = S2*S2 (cm) ; V0 = U0 + U1*S2 ; V1 = U2 + U3*S2
//   L3: A = V0(fp16 acc-preload) + V1*S4
//   apply: out = A @ X as ONE 1024 x 8192 x 1024 GEMM
//
// R7 changes vs R5 (best, 186.9):
//  (a) tree GEMMs: 3-STAGE LDS pipeline, prefetch distance 2 (~440+ cyc
//      latency cover vs 1-step's ~220), ONE barrier + ONE counted vmcnt
//      per K-step. The lgkm trailing barrier is gone: with 3 buffers the
//      overwrite target was consumed last iteration, and barrier-pass
//      implies those ds_reads completed (each fed an MFMA pre-barrier).
//  (b) outCm epilogue packs 4 cm-contiguous rows -> one 8B store (was
//      4x 2B scatter).
//  (c) S rm+cm conversion via LDS-transpose block (coalesced uint4 cm
//      writes; was 1M x 2B stride-2KB scatter).
// R6 lesson: tree needs waves/CU (TLP) -- single-wave blocks starve SIMDs.
// Apply keeps R5's 128^2 4-wave counted-vmcnt structure (unchanged).

#define NN 1024
#define NBATCH 128
#define DDIM 64

typedef float floatx4 __attribute__((ext_vector_type(4)));
typedef _Float16 f16x8 __attribute__((ext_vector_type(8)));
typedef unsigned short u16;

__device__ __forceinline__ u16 f2h(float f) {
  union { _Float16 h; u16 u; } v; v.h = (_Float16)f; return v.u;
}
__device__ __forceinline__ float h2f(u16 u) {
  union { _Float16 h; u16 u; } v; v.u = u; return (float)v.h;
}

__device__ __forceinline__ void gll16(const void* g, void* l) {
  __builtin_amdgcn_global_load_lds(
      (const __attribute__((address_space(1))) void*)g,
      (__attribute__((address_space(3))) void*)l, 16, 0, 0);
}

// counted vmcnt wait (literal table)
template <int N>
__device__ __forceinline__ void vm_wait() {
  static_assert(N == 0 || N == 4 || N == 6 || N == 8, "literal table");
  if constexpr (N == 0) asm volatile("s_waitcnt vmcnt(0)" ::: "memory");
  else if constexpr (N == 4) asm volatile("s_waitcnt vmcnt(4)" ::: "memory");
  else if constexpr (N == 6) asm volatile("s_waitcnt vmcnt(6)" ::: "memory");
  else if constexpr (N == 8) asm volatile("s_waitcnt vmcnt(8)" ::: "memory");
}
__device__ __forceinline__ void barrier() {
  asm volatile("s_barrier" ::: "memory");
}
__device__ __forceinline__ void lgkm0() {
  asm volatile("s_waitcnt lgkmcnt(0)" ::: "memory");
}

// Stage ROWS x 64 u16 tile (row stride NN) into linear LDS, 16B chunks
// XOR-swizzled by row&7. Conflict-free on DMA write and ds_read_b128.
// Issues ROWS/32 global_load_lds per wave.
template <int ROWS>
__device__ __forceinline__ void stage64(const u16* __restrict__ g, u16* lds,
                                        int wave, int lane) {
  const int r = lane >> 3, c = lane & 7;
  const int sw = (c ^ r) * 8;
#pragma unroll
  for (int i = 0; i < ROWS / 32; ++i) {
    const int rb = wave * (ROWS / 4) + i * 8;
    gll16(g + (size_t)(rb + r) * NN + sw, lds + rb * 64);
  }
}

// ---------------- prep: S transpose-cvt + W cvt + X transpose --------------
struct CvtJob { const float* src; u16* rm; u16* cm; };
struct CvtJobs { CvtJob j[5]; };  // j[0]=S (rm+cm), j[1..4]=W odd (rm)

// blocks [0,256): S 64x64 transpose-cvt tiles (rm + coalesced cm)
// blocks [256,4352): W cvt rm (job = 1 + (bid-256)>>10)
// blocks [4352,6400): X transpose
__global__ __launch_bounds__(256) void prep_kernel(CvtJobs jobs,
                                                   const float* __restrict__ X,
                                                   u16* __restrict__ XT) {
  __shared__ u16 T[64][72];
  const int bid = blockIdx.x;
  const int t = threadIdx.x;
  if (bid < 256) {
    // S tile (tr,tc): read gs coalesced, write rm direct + cm transposed
    const CvtJob jb = jobs.j[0];
    const int tr = bid >> 4, tc = bid & 15;
#pragma unroll
    for (int it = 0; it < 4; ++it) {
      int lr = (t >> 4) + it * 16;
      int lc4 = (t & 15) * 4;
      size_t gidx = (size_t)(tr * 64 + lr) * NN + tc * 64 + lc4;
      float4 f = *(const float4*)&jb.src[gidx];
      u16 h[4] = { f2h(f.x), f2h(f.y), f2h(f.z), f2h(f.w) };
      uint2 p;
      p.x = (uint32_t)h[0] | ((uint32_t)h[1] << 16);
      p.y = (uint32_t)h[2] | ((uint32_t)h[3] << 16);
      *(uint2*)&jb.rm[gidx] = p;
      T[lc4 + 0][lr] = h[0];
      T[lc4 + 1][lr] = h[1];
      T[lc4 + 2][lr] = h[2];
      T[lc4 + 3][lr] = h[3];
    }
    __syncthreads();
#pragma unroll
    for (int it = 0; it < 2; ++it) {
      int lc = (t >> 3) + it * 32;
      int lr8 = (t & 7) * 8;
      *(uint4*)&jb.cm[(size_t)(tc * 64 + lc) * NN + tr * 64 + lr8] =
          *(uint4*)&T[lc][lr8];
    }
  } else if (bid < 4352) {
    const int wb = bid - 256;
    const CvtJob jb = jobs.j[1 + (wb >> 10)];
    int idx4 = (wb & 1023) * 256 + t;
    int e = idx4 * 4;
    float4 f = ((const float4*)jb.src)[idx4];
    uint2 p;
    p.x = (uint32_t)f2h(f.x) | ((uint32_t)f2h(f.y) << 16);
    p.y = (uint32_t)f2h(f.z) | ((uint32_t)f2h(f.w) << 16);
    *(uint2*)&jb.rm[e] = p;
  } else {
    const int tb = bid - 4352;
    const int k0 = (tb & 15) * 64;
    const int b = tb >> 4;
#pragma unroll
    for (int it = 0; it < 4; ++it) {
      int kr = (t >> 4) + it * 16;
      int d4 = (t & 15) * 4;
      float4 f = *(const float4*)&X[((size_t)b * NN + k0 + kr) * DDIM + d4];
      T[d4 + 0][kr] = f2h(f.x);
      T[d4 + 1][kr] = f2h(f.y);
      T[d4 + 2][kr] = f2h(f.z);
      T[d4 + 3][kr] = f2h(f.w);
    }
    __syncthreads();
#pragma unroll
    for (int it = 0; it < 2; ++it) {
      int d = (t >> 3) + it * 32;
      int kc = (t & 7) * 8;
      *(uint4*)&XT[((size_t)b * DDIM + d) * NN + k0 + kc] = *(uint4*)&T[d][kc];
    }
  }
}

// ---------------- fp16 GEMM: out = [add +] A*B, 3-stage pipeline -----------
struct GemmJob {
  const u16* A;        // fp16 row-major MxK
  const u16* B;        // fp16 col-major: (k,n) at [n*NN+k]
  const float* addF;   // optional fp32 additive (row-major, acc-preloaded)
  const u16* addH;     // optional fp16 additive (row-major, acc-preloaded)
  u16* outRm;          // optional fp16 row-major out
  u16* outCm;          // optional fp16 col-major out (packed 8B stores)
};
struct GemmJobs { GemmJob j[5]; };

template <int BM, int BN, int WM, int WN>
__global__ __launch_bounds__(256) void gemm_f16(GemmJobs jobs) {
  const GemmJob jb = jobs.j[blockIdx.z];
  __shared__ alignas(16) u16 As[3][BM * 64];
  __shared__ alignas(16) u16 Bs[3][BN * 64];
  const int t = threadIdx.x, wave = t >> 6, lane = t & 63;
  const int wm = wave / WN, wn = wave % WN;
  const int lm = lane & 15, q = lane >> 4;
  const int bm = blockIdx.x * BM, bn = blockIdx.y * BN;
  constexpr int MI = BM / (WM * 16), NI = BN / (WN * 16);
  constexpr int VMC = (BM + BN) / 32;  // stage loads per wave per K-step
  floatx4 acc[MI][NI] = {};

  const u16* Ag = jb.A + (size_t)bm * NN;
  const u16* Bg = jb.B + (size_t)bn * NN;

  // Preload additive operand into acc fragments (latency hides under K-loop)
  if (jb.addF) {
#pragma unroll
    for (int mi = 0; mi < MI; ++mi)
#pragma unroll
      for (int ni = 0; ni < NI; ++ni)
#pragma unroll
        for (int r = 0; r < 4; ++r) {
          int row = bm + wm * (BM / WM) + mi * 16 + q * 4 + r;
          int col = bn + wn * (BN / WN) + ni * 16 + lm;
          acc[mi][ni][r] = jb.addF[(size_t)row * NN + col];
        }
  } else if (jb.addH) {
#pragma unroll
    for (int mi = 0; mi < MI; ++mi)
#pragma unroll
      for (int ni = 0; ni < NI; ++ni)
#pragma unroll
        for (int r = 0; r < 4; ++r) {
          int row = bm + wm * (BM / WM) + mi * 16 + q * 4 + r;
          int col = bn + wn * (BN / WN) + ni * 16 + lm;
          acc[mi][ni][r] = h2f(jb.addH[(size_t)row * NN + col]);
        }
  }

  // prologue: tiles 0 and 1 in flight (2*VMC loads, oldest = tile 0)
  stage64<BM>(Ag, As[0], wave, lane);
  stage64<BN>(Bg, Bs[0], wave, lane);
  stage64<BM>(Ag + 64, As[1], wave, lane);
  stage64<BN>(Bg + 64, Bs[1], wave, lane);

  for (int kk = 0; kk < 16; ++kk) {
    const int cur = kk % 3;
    // tile kk's VMC loads landed; tile kk+1's stay in flight
    if (kk < 15) vm_wait<VMC>(); else vm_wait<0>();
    barrier();  // all waves: tile kk resident AND tile kk-1 reads done
    // read all frags of tile kk
    f16x8 af[2][MI], bf[2][NI];
#pragma unroll
    for (int ks = 0; ks < 2; ++ks) {
      const int st = ((ks * 4 + q) ^ (lm & 7)) * 8;
#pragma unroll
      for (int ni = 0; ni < NI; ++ni)
        bf[ks][ni] = *(const f16x8*)&Bs[cur][(wn * (BN / WN) + ni * 16 + lm) * 64 + st];
#pragma unroll
      for (int mi = 0; mi < MI; ++mi)
        af[ks][mi] = *(const f16x8*)&As[cur][(wm * (BM / WM) + mi * 16 + lm) * 64 + st];
    }
    // stage tile kk+2 into the buffer consumed at iteration kk-1
    if (kk + 2 < 16) {
      stage64<BM>(Ag + (kk + 2) * 64, As[(kk + 2) % 3], wave, lane);
      stage64<BN>(Bg + (kk + 2) * 64, Bs[(kk + 2) % 3], wave, lane);
    }
#pragma unroll
    for (int ks = 0; ks < 2; ++ks)
#pragma unroll
      for (int mi = 0; mi < MI; ++mi)
#pragma unroll
        for (int ni = 0; ni < NI; ++ni)
          acc[mi][ni] = __builtin_amdgcn_mfma_f32_16x16x32_f16(
              af[ks][mi], bf[ks][ni], acc[mi][ni], 0, 0, 0);
  }

#pragma unroll
  for (int mi = 0; mi < MI; ++mi)
#pragma unroll
    for (int ni = 0; ni < NI; ++ni) {
      int row0 = bm + wm * (BM / WM) + mi * 16 + q * 4;
      int col = bn + wn * (BN / WN) + ni * 16 + lm;
      u16 h[4];
#pragma unroll
      for (int r = 0; r < 4; ++r) h[r] = f2h(acc[mi][ni][r]);
      if (jb.outRm) {
#pragma unroll
        for (int r = 0; r < 4; ++r)
          jb.outRm[(size_t)(row0 + r) * NN + col] = h[r];
      }
      if (jb.outCm) {  // rows are cm-contiguous: one 8B store
        uint2 p;
        p.x = (uint32_t)h[0] | ((uint32_t)h[1] << 16);
        p.y = (uint32_t)h[2] | ((uint32_t)h[3] << 16);
        *(uint2*)&jb.outCm[(size_t)col * NN + row0] = p;
      }
    }
}

// ---------------- apply: one 1024 x 8192 x 1024 GEMM (R5, unchanged) -------
__global__ __launch_bounds__(256) void apply_gemm(const u16* __restrict__ A,
                                                  const u16* __restrict__ XT,
                                                  float* __restrict__ out) {
  __shared__ alignas(16) u16 As[2][128 * 64], Xs[2][128 * 64];  // 64 KB
  const int t = threadIdx.x, wave = t >> 6, lane = t & 63;
  const int wm = wave >> 1, wn = wave & 1;
  const int lm = lane & 15, q = lane >> 4;
  const int bn = blockIdx.x * 128;  // column tile (b*64+d)
  const int bm = blockIdx.y * 128;  // A row tile
  floatx4 acc[4][4] = {};
  const u16* Ag = A + (size_t)bm * NN;
  const u16* Xg = XT + (size_t)bn * NN;

  stage64<128>(Ag, As[0], wave, lane);
  stage64<128>(Xg, Xs[0], wave, lane);

  for (int kt = 0; kt < 16; ++kt) {
    const int cur = kt & 1;
    if (kt + 1 < 16) {
      stage64<128>(Ag + (kt + 1) * 64, As[cur ^ 1], wave, lane);
      stage64<128>(Xg + (kt + 1) * 64, Xs[cur ^ 1], wave, lane);
      vm_wait<8>();  // tile kt landed; kt+1's 8 loads in flight
    } else {
      vm_wait<0>();
    }
    barrier();
#pragma unroll
    for (int ks = 0; ks < 2; ++ks) {
      const int st = ((ks * 4 + q) ^ (lm & 7)) * 8;
      f16x8 xf[4];
#pragma unroll
      for (int ni = 0; ni < 4; ++ni)
        xf[ni] = *(const f16x8*)&Xs[cur][(wn * 64 + ni * 16 + lm) * 64 + st];
#pragma unroll
      for (int mi = 0; mi < 4; ++mi) {
        f16x8 a = *(const f16x8*)&As[cur][(wm * 64 + mi * 16 + lm) * 64 + st];
#pragma unroll
        for (int ni = 0; ni < 4; ++ni)
          acc[mi][ni] = __builtin_amdgcn_mfma_f32_16x16x32_f16(a, xf[ni], acc[mi][ni], 0, 0, 0);
      }
    }
    lgkm0();
    barrier();
  }

#pragma unroll
  for (int mi = 0; mi < 4; ++mi)
#pragma unroll
    for (int ni = 0; ni < 4; ++ni)
#pragma unroll
      for (int r = 0; r < 4; ++r) {
        int row = bm + wm * 64 + mi * 16 + q * 4 + r;
        int col = bn + wn * 64 + ni * 16 + lm;  // = b*64 + d
        out[((size_t)(col >> 6) * NN + row) * DDIM + (col & 63)] =
            acc[mi][ni][r];
      }
}

extern "C" void kernel_launch(void* const* d_in, const int* in_sizes, int n_in,
                              void* d_out, int out_size, void* d_ws, size_t ws_size,
                              hipStream_t stream) {
  const float* nodes  = (const float*)d_in[0];  // [128,1024,64]
  const float* weight = (const float*)d_in[1];  // [8,1024,1024]
  const float* gs     = (const float*)d_in[2];  // [1024,1024]
  float* out = (float*)d_out;
  u16* ws = (u16*)d_ws;
  const size_t MB = (size_t)NN * NN;
  auto buf = [&](int i) -> u16* { return ws + (size_t)i * MB; };
  // 2MB fp16 slots: 0 S rm | 1 S cm | 2..5 W1,3,5,7 rm | 6 S2 rm | 7 S2 cm
  // 8..11 U0..U3 | 12 S4 cm | 13 V0 | 14 V1 | 15 A | 16..23 XT (16 MB)

  u16* XT = buf(16);
  CvtJobs cv{};
  cv.j[0] = { gs,              buf(0), buf(1) };
  cv.j[1] = { weight + 1 * MB, buf(2), nullptr };
  cv.j[2] = { weight + 3 * MB, buf(3), nullptr };
  cv.j[3] = { weight + 5 * MB, buf(4), nullptr };
  cv.j[4] = { weight + 7 * MB, buf(5), nullptr };
  prep_kernel<<<dim3(6400), 256, 0, stream>>>(cv, nodes, XT);

  // L1: S2 = S*S ; U_j = W_{2j}(acc-preload) + W_{2j+1}*S
  // 64x128 tiles, grid 640, LDS 72KB 3-stage (2 blocks/CU)
  GemmJobs g1{};
  g1.j[0] = { buf(0), buf(1), nullptr,         nullptr, buf(6),  buf(7)  };
  g1.j[1] = { buf(2), buf(1), weight + 0 * MB, nullptr, buf(8),  nullptr };
  g1.j[2] = { buf(3), buf(1), weight + 2 * MB, nullptr, buf(9),  nullptr };
  g1.j[3] = { buf(4), buf(1), weight + 4 * MB, nullptr, buf(10), nullptr };
  g1.j[4] = { buf(5), buf(1), weight + 6 * MB, nullptr, buf(11), nullptr };
  gemm_f16<64, 128, 2, 2><<<dim3(16, 8, 5), 256, 0, stream>>>(g1);

  // L2: S4 = S2*S2 (cm) ; V0 = U0 + U1*S2 ; V1 = U2 + U3*S2
  // 64x64 tiles, grid 768, LDS 48KB 3-stage (3 blocks/CU)
  GemmJobs g2{};
  g2.j[0] = { buf(6),  buf(7), nullptr, nullptr, nullptr, buf(12) };
  g2.j[1] = { buf(9),  buf(7), nullptr, buf(8),  buf(13), nullptr };
  g2.j[2] = { buf(11), buf(7), nullptr, buf(10), buf(14), nullptr };
  gemm_f16<64, 64, 2, 2><<<dim3(16, 16, 3), 256, 0, stream>>>(g2);

  // L3: A = V0(fp16 acc-preload) + V1*S4 -- direct write (256 blocks)
  GemmJobs g3{};
  g3.j[0] = { buf(14), buf(12), nullptr, buf(13), buf(15), nullptr };
  gemm_f16<64, 64, 2, 2><<<dim3(16, 16, 1), 256, 0, stream>>>(g3);

  apply_gemm<<<dim3(64, 8), 256, 0, stream>>>(buf(15), XT, out);
}